// Round 3
// baseline (219.542 us; speedup 1.0000x reference)
//
#include <hip/hip_runtime.h>

#define H 64
#define NEDGE 50000
#define NNODE 12000
#define EPAD 50176

typedef _Float16 f16;
typedef _Float16 h8 __attribute__((ext_vector_type(8)));
typedef float f4 __attribute__((ext_vector_type(4)));

// workspace layout (bytes)
#define O_EDGEH 0ull            // edge f16 padded [50176][64]      = 6,422,528
#define O_W2G   6422528ull      // swizzled W2 f16 (64 x 16KB)      = 1,048,576
#define O_W1G   7471104ull      // swizzled W1 f16 (must follow W2G: tail overread lands here)
#define O_WG    7487488ull      // GRU combined weights f16 [128k][256n] granules = 65,536
#define O_NB    7553024ull      // nb[i][n] = node[i,:] @ b2mat f32 = 3,072,000
#define O_AGG   10625024ull     // agg f32 [12000][64]              = 3,072,000

__device__ __forceinline__ void async16(const void* g, void* l) {
  __builtin_amdgcn_global_load_lds((const __attribute__((address_space(1))) void*)g,
                                   (__attribute__((address_space(3))) void*)l, 16, 0, 0);
}

// ---------------- prep: edge->f16 (8-wide), W2/W1/Wgru -> MFMA-B granule order, nb GEMM
__global__ __launch_bounds__(256) void k_prep(const float* __restrict__ edge, const float* __restrict__ W1,
                                              const float* __restrict__ W2, const float* __restrict__ b2,
                                              const float* __restrict__ node,
                                              const float* __restrict__ Wih, const float* __restrict__ Whh,
                                              f16* __restrict__ edgeh, f16* __restrict__ w1g, f16* __restrict__ w2g,
                                              f16* __restrict__ wg, float* __restrict__ nb) {
  int bid = blockIdx.x;
  int t = threadIdx.x;
  if (bid < 1568) {  // edgeh cast, 8 elems/thread
    long id8 = (long)bid * 256 + t;
    long e = id8 >> 3;
    int c = (int)(id8 & 7) * 8;
    h8 o = {};
    if (e < NEDGE) {
      const float* p = edge + e * 64 + c;
      f4 v0 = *(const f4*)p, v1 = *(const f4*)(p + 4);
#pragma unroll
      for (int j = 0; j < 4; ++j) { o[j] = (f16)v0[j]; o[4 + j] = (f16)v1[j]; }
    }
    *(h8*)(edgeh + e * 64 + c) = o;
    return;
  }
  if (bid < 3616) {  // w2g swizzle: 524288 elems
    int id = (bid - 1568) * 256 + t;
    int ii = id & 7, l = (id >> 3) & 63, t4 = (id >> 9) & 3, s = (id >> 11) & 3, h = id >> 13;
    int n = t4 * 16 + (l & 15), j = s * 32 + ((l >> 4) << 3) + ii;
    w2g[id] = (f16)W2[(h * 64 + n) * 128 + j];
    return;
  }
  if (bid < 3648) {  // w1g: 8192 elems
    int id = (bid - 3616) * 256 + t;
    int ii = id & 7, l = (id >> 3) & 63, tt = (id >> 9) & 7, s = id >> 12;
    int n = tt * 16 + (l & 15), k = s * 32 + ((l >> 4) << 3) + ii;
    w1g[id] = (f16)W1[n * 64 + k];
    return;
  }
  if (bid < 3776) {  // wg: GRU combined B matrix [128k][256n], 32768 elems
    int id = (bid - 3648) * 256 + t;
    int ii = id & 7, l = (id >> 3) & 63, tt = (id >> 9) & 15, s = id >> 13;
    int k = s * 32 + ((l >> 4) << 3) + ii, n = tt * 16 + (l & 15);
    float v;
    if (n < 128) v = (k < 64) ? Wih[n * 64 + k] : Whh[n * 64 + (k - 64)];       // r,z summed
    else if (n < 192) v = (k < 64) ? Wih[n * 64 + k] : 0.f;                      // gi_n
    else v = (k < 64) ? 0.f : Whh[(n - 64) * 64 + (k - 64)];                     // gh_n
    wg[id] = (f16)v;
    return;
  }
  // nb: nb[i][n] = sum_a node[i][a] * b2[a*64+n]
  __shared__ float bs[64][65];
  __shared__ float xs[64][65];
  int n0 = (bid - 3776) * 64;
#pragma unroll
  for (int it = 0; it < 16; ++it) {
    int idx = t + it * 256;
    int rr = idx >> 6, cc = idx & 63;
    bs[rr][cc] = b2[idx];
    int nn = n0 + rr;
    xs[rr][cc] = (nn < NNODE) ? node[(long)nn * 64 + cc] : 0.f;
  }
  __syncthreads();
  int f0 = (t & 15) * 4, e0 = (t >> 4) * 4;
  float acc[4][4] = {};
#pragma unroll 4
  for (int k = 0; k < 64; ++k) {
    f4 w = *(const f4*)&bs[k][f0];
#pragma unroll
    for (int i = 0; i < 4; ++i) {
      float x = xs[e0 + i][k];
      acc[i][0] = fmaf(x, w[0], acc[i][0]); acc[i][1] = fmaf(x, w[1], acc[i][1]);
      acc[i][2] = fmaf(x, w[2], acc[i][2]); acc[i][3] = fmaf(x, w[3], acc[i][3]);
    }
  }
#pragma unroll
  for (int i = 0; i < 4; ++i) {
    int nn = n0 + e0 + i;
    if (nn < NNODE)
#pragma unroll
      for (int j = 0; j < 4; ++j) nb[(long)nn * 64 + f0 + j] = acc[i][j];
  }
}

// ---------------- fused msg kernel: 64 edges/block, 4 waves (M=64, N=16 each).
// edge-MLP via MFMA -> eh fragments to registers -> barrier-free K-loop with B
// double-buffered in REGISTERS from L2 (no __syncthreads in the hot loop).
__global__ __launch_bounds__(256, 3) void k_msg(const float* __restrict__ node,
                                                const int* __restrict__ src, const int* __restrict__ dst,
                                                const f16* __restrict__ edgeh, const f16* __restrict__ w1g,
                                                const f16* __restrict__ w2g, const float* __restrict__ b1,
                                                const float* __restrict__ nbt, float* __restrict__ agg) {
  __shared__ __align__(16) f16 est[64 * 8 * 8];    // edge tile, swizzled granules (8 KB)
  __shared__ __align__(16) f16 eh_s[64 * 16 * 8];  // eh tile, swizzled granules (16 KB)
  __shared__ __align__(16) f16 vT2[64 * 8 * 8];    // v[e][h] f16, swizzled granules (8 KB)
  __shared__ int ssrc[64];
  __shared__ int sdst[64];
  __shared__ float b1s[128];

  int t = threadIdx.x;
  int e_base = blockIdx.x * 64;

  // ---- phase 0: indices, b1, edge tile (async DMA), v gather -> vT2
  if (t < 64) {
    int eg = e_base + t;
    bool valid = eg < NEDGE;
    ssrc[t] = valid ? src[eg] : 0;
    sdst[t] = valid ? dst[eg] : 0;
  }
  if (t >= 128) b1s[t - 128] = b1[t - 128];
  {
    const char* ehb = (const char*)edgeh;
#pragma unroll
    for (int r = 0; r < 2; ++r) {
      int idx = r * 256 + t;
      int e = idx >> 3, c1 = idx & 7;
      int c = c1 ^ (e & 7);
      async16(ehb + ((long)(e_base + e) * 8 + c) * 16, (char*)est + idx * 16);
    }
  }
  {
    int e = t >> 2, q = t & 3;
    int eg = e_base + e;
    int si = (eg < NEDGE) ? src[eg] : 0;
    const f4* nr = (const f4*)(node + (long)si * 64 + q * 16);
    f4 a0 = nr[0], a1 = nr[1], a2 = nr[2], a3 = nr[3];
    h8 p0, p1;
#pragma unroll
    for (int m = 0; m < 4; ++m) {
      p0[m] = (f16)a0[m]; p0[4 + m] = (f16)a1[m];
      p1[m] = (f16)a2[m]; p1[4 + m] = (f16)a3[m];
    }
    int g0 = (q * 2) ^ (e & 7), g1 = (q * 2 + 1) ^ (e & 7);
    *(h8*)(vT2 + (e * 8 + g0) * 8) = p0;   // covers h = q*16 .. q*16+7
    *(h8*)(vT2 + (e * 8 + g1) * 8) = p1;   // covers h = q*16+8 .. q*16+15
  }
  __syncthreads();

  int wave = t >> 6, lane = t & 63;
  int l15 = lane & 15, lq = lane >> 4;

  // ---- phase 1: eh = relu(edge @ W1^T + b1), M=64 (all waves), wave n-cols [w*32, w*32+32)
  {
    h8 afr[4][2];
#pragma unroll
    for (int g = 0; g < 4; ++g) {
      int e = g * 16 + l15;
#pragma unroll
      for (int s = 0; s < 2; ++s) {
        int c = (s * 4 + lq) ^ (e & 7);
        afr[g][s] = *(const h8*)(est + (e * 8 + c) * 8);
      }
    }
    h8 bfr[2][2];
#pragma unroll
    for (int s = 0; s < 2; ++s)
#pragma unroll
      for (int j = 0; j < 2; ++j)
        bfr[s][j] = *(const h8*)(w1g + ((s * 8 + wave * 2 + j) * 64 + lane) * 8);
    f4 acc_eh[4][2];
#pragma unroll
    for (int g = 0; g < 4; ++g) { acc_eh[g][0] = (f4){0,0,0,0}; acc_eh[g][1] = (f4){0,0,0,0}; }
#pragma unroll
    for (int s = 0; s < 2; ++s)
#pragma unroll
      for (int g = 0; g < 4; ++g)
#pragma unroll
        for (int j = 0; j < 2; ++j)
          acc_eh[g][j] = __builtin_amdgcn_mfma_f32_16x16x32_f16(afr[g][s], bfr[s][j], acc_eh[g][j], 0, 0, 0);
    // write eh tile to LDS (swizzled granules), + b1 + relu
#pragma unroll
    for (int g = 0; g < 4; ++g)
#pragma unroll
      for (int j = 0; j < 2; ++j) {
        int n = wave * 32 + j * 16 + l15;
        int jg = n >> 3;
#pragma unroll
        for (int r = 0; r < 4; ++r) {
          int e = g * 16 + lq * 4 + r;
          float val = fmaxf(acc_eh[g][j][r] + b1s[n], 0.f);
          eh_s[(e * 16 + (jg ^ (e & 15))) * 8 + (n & 7)] = (f16)val;
        }
      }
  }
  __syncthreads();

  // ---- phase 2: eh fragments -> registers (period-128 in K)
  h8 ehreg[4][4];
#pragma unroll
  for (int g = 0; g < 4; ++g) {
    int e = g * 16 + l15;
#pragma unroll
    for (int s = 0; s < 4; ++s) {
      int jg = (s * 4 + lq) ^ (e & 15);
      ehreg[g][s] = *(const h8*)(eh_s + (e * 16 + jg) * 8);
    }
  }
  // NO more barriers: B streams from L2 into registers.

  // ---- phase 3: K-loop over 64 h (K=128 each), B register double-buffer
  f4 acc[4];
#pragma unroll
  for (int g = 0; g < 4; ++g) acc[g] = (f4){0.f, 0.f, 0.f, 0.f};

  const char* w2b = (const char*)w2g + wave * 1024 + lane * 16;
  h8 cur0 = *(const h8*)(w2b);
  h8 cur1 = *(const h8*)(w2b + 4096);
  h8 cur2 = *(const h8*)(w2b + 8192);
  h8 cur3 = *(const h8*)(w2b + 12288);

#pragma unroll 1
  for (int hb = 0; hb < 8; ++hb) {
    h8 vh8[4];
#pragma unroll
    for (int g = 0; g < 4; ++g) {
      int e = g * 16 + l15;
      vh8[g] = *(const h8*)(vT2 + (e * 8 + (hb ^ (e & 7))) * 8);
    }
#pragma unroll
    for (int hh = 0; hh < 8; ++hh) {
      int h = hb * 8 + hh;
      const char* gp = w2b + (long)(h + 1) * 16384;  // h=63 overreads into w1g: harmless
      h8 pf0 = *(const h8*)(gp);
      h8 pf1 = *(const h8*)(gp + 4096);
      h8 pf2 = *(const h8*)(gp + 8192);
      h8 pf3 = *(const h8*)(gp + 12288);
      f16 vs;
#pragma unroll
      for (int g = 0; g < 4; ++g) {
        vs = vh8[g][hh];
        h8 a = ehreg[g][0] * vs;
        acc[g] = __builtin_amdgcn_mfma_f32_16x16x32_f16(a, cur0, acc[g], 0, 0, 0);
        a = ehreg[g][1] * vs;
        acc[g] = __builtin_amdgcn_mfma_f32_16x16x32_f16(a, cur1, acc[g], 0, 0, 0);
        a = ehreg[g][2] * vs;
        acc[g] = __builtin_amdgcn_mfma_f32_16x16x32_f16(a, cur2, acc[g], 0, 0, 0);
        a = ehreg[g][3] * vs;
        acc[g] = __builtin_amdgcn_mfma_f32_16x16x32_f16(a, cur3, acc[g], 0, 0, 0);
      }
      cur0 = pf0; cur1 = pf1; cur2 = pf2; cur3 = pf3;
    }
  }

  // ---- epilogue: + nb[src], atomic scatter to agg[dst].  n = wave*16 + l15
  int n = wave * 16 + l15;
#pragma unroll
  for (int g = 0; g < 4; ++g)
#pragma unroll
    for (int r = 0; r < 4; ++r) {
      int el = g * 16 + lq * 4 + r;
      if (e_base + el < NEDGE) {
        float v = acc[g][r] + nbt[(long)ssrc[el] * 64 + n];
        atomicAdd(&agg[(long)sdst[el] * 64 + n], v);
      }
    }
}

// ---------------- GRU + LayerNorm via MFMA: 128 nodes/block, 4 waves M-split (32 nodes each).
// One K=128 GEMM (A=[relu(agg)|hid] f16) x Wcat[128][256]: cols 0-63 r_sum, 64-127 z_sum,
// 128-191 gi_n, 192-255 gh_n. Epilogue: gates + GRU + LN with 8 shfl per node-slot.
__global__ __launch_bounds__(256) void k_node(const float* __restrict__ agg, const float* __restrict__ hid,
                                              const f16* __restrict__ wg,
                                              const float* __restrict__ bih, const float* __restrict__ bhh,
                                              const float* __restrict__ gamma, const float* __restrict__ beta,
                                              float* __restrict__ out) {
  __shared__ __align__(16) f16 xh_s[128 * 136];
  __shared__ float bsum[128], bin_s[64], bhn_s[64], gam_s[64], bet_s[64];
  int t = threadIdx.x;
  int n0 = blockIdx.x * 128;

  if (t < 128) bsum[t] = bih[t] + bhh[t];
  else if (t < 192) bin_s[t - 128] = bih[t];          // b_ih[128+f]
  else bhn_s[t - 192] = bhh[t - 64];                  // b_hh[128+f]
  if (t < 64) gam_s[t] = gamma[t];
  else if (t < 128) bet_s[t - 64] = beta[t - 64];

  {  // stage A = [relu(agg) | hid] as f16
    int m = t >> 1, half = t & 1;
    int mg = n0 + m;
    bool vld = mg < NNODE;
    const float* sp = half ? (hid + (long)mg * 64) : (agg + (long)mg * 64);
#pragma unroll
    for (int jj = 0; jj < 8; ++jj) {
      f4 v0 = {0,0,0,0}, v1 = {0,0,0,0};
      if (vld) { v0 = *(const f4*)(sp + jj * 8); v1 = *(const f4*)(sp + jj * 8 + 4); }
      h8 pk;
#pragma unroll
      for (int m2 = 0; m2 < 4; ++m2) {
        pk[m2] = (f16)(half ? v0[m2] : fmaxf(v0[m2], 0.f));
        pk[4 + m2] = (f16)(half ? v1[m2] : fmaxf(v1[m2], 0.f));
      }
      *(h8*)(xh_s + m * 136 + half * 64 + jj * 8) = pk;
    }
  }
  __syncthreads();

  int wave = t >> 6, lane = t & 63;
  int l15 = lane & 15, lq = lane >> 4;

  f4 acc[2][16];
#pragma unroll
  for (int g = 0; g < 2; ++g)
#pragma unroll
    for (int tt = 0; tt < 16; ++tt) acc[g][tt] = (f4){0.f, 0.f, 0.f, 0.f};

#pragma unroll
  for (int s = 0; s < 4; ++s) {
    h8 a0 = *(const h8*)(xh_s + (wave * 32 + l15) * 136 + s * 32 + lq * 8);
    h8 a1 = *(const h8*)(xh_s + (wave * 32 + 16 + l15) * 136 + s * 32 + lq * 8);
#pragma unroll
    for (int tt = 0; tt < 16; ++tt) {
      h8 b = *(const h8*)(wg + ((s * 16 + tt) * 64 + lane) * 8);
      acc[0][tt] = __builtin_amdgcn_mfma_f32_16x16x32_f16(a0, b, acc[0][tt], 0, 0, 0);
      acc[1][tt] = __builtin_amdgcn_mfma_f32_16x16x32_f16(a1, b, acc[1][tt], 0, 0, 0);
    }
  }

  // epilogue
#pragma unroll
  for (int g = 0; g < 2; ++g)
#pragma unroll
    for (int r = 0; r < 4; ++r) {
      int mg = n0 + wave * 32 + g * 16 + lq * 4 + r;
      bool vld = mg < NNODE;
      float o[4], ssum = 0.f, s2 = 0.f;
#pragma unroll
      for (int t0 = 0; t0 < 4; ++t0) {
        int f = t0 * 16 + l15;
        float rpre = acc[g][t0][r] + bsum[f];
        float zpre = acc[g][4 + t0][r] + bsum[64 + f];
        float ginv = acc[g][8 + t0][r] + bin_s[f];
        float ghnv = acc[g][12 + t0][r] + bhn_s[f];
        float rr = 1.f / (1.f + __expf(-rpre));
        float zz = 1.f / (1.f + __expf(-zpre));
        float hv = vld ? hid[(long)mg * 64 + f] : 0.f;
        float nn = tanhf(ginv + rr * ghnv);
        float oo = (1.f - zz) * nn + zz * hv;
        o[t0] = oo; ssum += oo; s2 += oo * oo;
      }
#pragma unroll
      for (int d = 1; d < 16; d <<= 1) {
        ssum += __shfl_xor(ssum, d);
        s2 += __shfl_xor(s2, d);
      }
      float mu = ssum * (1.f / 64.f);
      float var = s2 * (1.f / 64.f) - mu * mu;
      float rstd = rsqrtf(var + 1e-5f);
      if (vld)
#pragma unroll
        for (int t0 = 0; t0 < 4; ++t0) {
          int f = t0 * 16 + l15;
          out[(long)mg * 64 + f] = (o[t0] - mu) * rstd * gam_s[f] + bet_s[f];
        }
    }
}

extern "C" void kernel_launch(void* const* d_in, const int* in_sizes, int n_in,
                              void* d_out, int out_size, void* d_ws, size_t ws_size,
                              hipStream_t stream) {
  const float* node = (const float*)d_in[0];
  const float* edge = (const float*)d_in[1];
  const float* hid = (const float*)d_in[2];
  const int* src = (const int*)d_in[3];
  const int* dst = (const int*)d_in[4];
  const float* W1 = (const float*)d_in[5];
  const float* b1 = (const float*)d_in[6];
  const float* W2 = (const float*)d_in[7];
  const float* b2 = (const float*)d_in[8];
  const float* Wih = (const float*)d_in[9];
  const float* Whh = (const float*)d_in[10];
  const float* bih = (const float*)d_in[11];
  const float* bhh = (const float*)d_in[12];
  const float* gamma = (const float*)d_in[13];
  const float* beta = (const float*)d_in[14];

  char* ws = (char*)d_ws;
  f16* edgeh = (f16*)(ws + O_EDGEH);
  f16* w2g = (f16*)(ws + O_W2G);
  f16* w1g = (f16*)(ws + O_W1G);
  f16* wg = (f16*)(ws + O_WG);
  float* nb = (float*)(ws + O_NB);
  float* agg = (float*)(ws + O_AGG);

  hipMemsetAsync(agg, 0, (size_t)NNODE * 64 * sizeof(float), stream);
  k_prep<<<3964, 256, 0, stream>>>(edge, W1, W2, b2, node, Wih, Whh, edgeh, w1g, w2g, wg, nb);
  k_msg<<<784, 256, 0, stream>>>(node, src, dst, edgeh, w1g, w2g, b1, nb, agg);
  k_node<<<94, 256, 0, stream>>>(agg, hid, wg, bih, bhh, gamma, beta, (float*)d_out);
}

// Round 4
// 214.240 us; speedup vs baseline: 1.0247x; 1.0247x over previous
//
#include <hip/hip_runtime.h>

#define H 64
#define NEDGE 50000
#define NNODE 12000
#define EPAD 50176

typedef _Float16 f16;
typedef _Float16 h8 __attribute__((ext_vector_type(8)));
typedef float f4 __attribute__((ext_vector_type(4)));

// workspace layout (bytes)
#define O_EDGEH 0ull            // edge f16 padded [50176][64]      = 6,422,528
#define O_W2G   6422528ull      // swizzled W2 f16 (64 x 16KB)      = 1,048,576
#define O_W1G   7471104ull      // swizzled W1 f16 (16KB; must follow W2G: K-loop tail overread)
#define O_WG    7487488ull      // GRU combined weights f16 (64KB; absorbs 2nd half of tail overread)
#define O_NB    7553024ull      // nb[i][n] = node[i,:] @ b2mat f32 = 3,072,000
#define O_AGG   10625024ull     // agg f32 [12000][64]              = 3,072,000

__device__ __forceinline__ void async16(const void* g, void* l) {
  __builtin_amdgcn_global_load_lds((const __attribute__((address_space(1))) void*)g,
                                   (__attribute__((address_space(3))) void*)l, 16, 0, 0);
}

// ---------------- prep: agg zero, edge->f16, W2/W1/Wgru -> MFMA-B granule order, nb GEMM
__global__ __launch_bounds__(256) void k_prep(const float* __restrict__ edge, const float* __restrict__ W1,
                                              const float* __restrict__ W2, const float* __restrict__ b2,
                                              const float* __restrict__ node,
                                              const float* __restrict__ Wih, const float* __restrict__ Whh,
                                              f16* __restrict__ edgeh, f16* __restrict__ w1g, f16* __restrict__ w2g,
                                              f16* __restrict__ wg, float* __restrict__ nb, float* __restrict__ agg) {
  int bid = blockIdx.x;
  int t = threadIdx.x;
  if (bid < 750) {  // agg zero: 750*256*4 = 768000 = 12000*64
    int id = bid * 256 + t;
    *(f4*)(agg + (long)id * 4) = (f4){0.f, 0.f, 0.f, 0.f};
    return;
  }
  if (bid < 2318) {  // edgeh cast, 8 elems/thread (covers EPAD rows, pad zeroed)
    long id8 = (long)(bid - 750) * 256 + t;
    long e = id8 >> 3;
    int c = (int)(id8 & 7) * 8;
    h8 o = {};
    if (e < NEDGE) {
      const float* p = edge + e * 64 + c;
      f4 v0 = *(const f4*)p, v1 = *(const f4*)(p + 4);
#pragma unroll
      for (int j = 0; j < 4; ++j) { o[j] = (f16)v0[j]; o[4 + j] = (f16)v1[j]; }
    }
    *(h8*)(edgeh + e * 64 + c) = o;
    return;
  }
  if (bid < 4366) {  // w2g swizzle: 524288 elems
    int id = (bid - 2318) * 256 + t;
    int ii = id & 7, l = (id >> 3) & 63, t4 = (id >> 9) & 3, s = (id >> 11) & 3, h = id >> 13;
    int n = t4 * 16 + (l & 15), j = s * 32 + ((l >> 4) << 3) + ii;
    w2g[id] = (f16)W2[(h * 64 + n) * 128 + j];
    return;
  }
  if (bid < 4398) {  // w1g: 8192 elems
    int id = (bid - 4366) * 256 + t;
    int ii = id & 7, l = (id >> 3) & 63, tt = (id >> 9) & 7, s = id >> 12;
    int n = tt * 16 + (l & 15), k = s * 32 + ((l >> 4) << 3) + ii;
    w1g[id] = (f16)W1[n * 64 + k];
    return;
  }
  if (bid < 4526) {  // wg: GRU combined B matrix [128k][256n], 32768 elems
    int id = (bid - 4398) * 256 + t;
    int ii = id & 7, l = (id >> 3) & 63, tt = (id >> 9) & 15, s = id >> 13;
    int k = s * 32 + ((l >> 4) << 3) + ii, n = tt * 16 + (l & 15);
    float v;
    if (n < 128) v = (k < 64) ? Wih[n * 64 + k] : Whh[n * 64 + (k - 64)];       // r,z summed
    else if (n < 192) v = (k < 64) ? Wih[n * 64 + k] : 0.f;                      // gi_n
    else v = (k < 64) ? 0.f : Whh[(n - 64) * 64 + (k - 64)];                     // gh_n
    wg[id] = (f16)v;
    return;
  }
  // nb: nb[i][n] = sum_a node[i][a] * b2[a*64+n]
  __shared__ float bs[64][65];
  __shared__ float xs[64][65];
  int n0 = (bid - 4526) * 64;
#pragma unroll
  for (int it = 0; it < 16; ++it) {
    int idx = t + it * 256;
    int rr = idx >> 6, cc = idx & 63;
    bs[rr][cc] = b2[idx];
    int nn = n0 + rr;
    xs[rr][cc] = (nn < NNODE) ? node[(long)nn * 64 + cc] : 0.f;
  }
  __syncthreads();
  int f0 = (t & 15) * 4, e0 = (t >> 4) * 4;
  float acc[4][4] = {};
#pragma unroll 4
  for (int k = 0; k < 64; ++k) {
    f4 w = *(const f4*)&bs[k][f0];
#pragma unroll
    for (int i = 0; i < 4; ++i) {
      float x = xs[e0 + i][k];
      acc[i][0] = fmaf(x, w[0], acc[i][0]); acc[i][1] = fmaf(x, w[1], acc[i][1]);
      acc[i][2] = fmaf(x, w[2], acc[i][2]); acc[i][3] = fmaf(x, w[3], acc[i][3]);
    }
  }
#pragma unroll
  for (int i = 0; i < 4; ++i) {
    int nn = n0 + e0 + i;
    if (nn < NNODE)
#pragma unroll
      for (int j = 0; j < 4; ++j) nb[(long)nn * 64 + f0 + j] = acc[i][j];
  }
}

// ---------------- fused msg kernel: 256 edges/block, 4 waves M-split (M=64, N=64 each).
// Phase 1: eh = relu(edge@W1^T+b1) via MFMA (A straight from global edgeh).
// Phase 3: K=8192 loop, eh fragments in registers, B LDS-double-buffered (32KB chunks)
// via global_load_lds; barrier per K=256 (32 total). A formed on the fly (4 pk_mul / frag,
// amortized over N=64 -> VALU:MFMA = 0.42).
__global__ __launch_bounds__(256, 2) void k_msg(const float* __restrict__ node,
                                                const int* __restrict__ src, const int* __restrict__ dst,
                                                const f16* __restrict__ edgeh, const f16* __restrict__ w1g,
                                                const f16* __restrict__ w2g, const float* __restrict__ b1,
                                                const float* __restrict__ nbt, float* __restrict__ agg) {
  // LDS: [0,65536) eh_s (phases 1-2) then Bdbuf 2x32KB (K-loop)
  //      [65536,102400) vT: 256 rows x 144B (64 h f16 used of 72)
  //      [102400,103424) ssrc | [103424,104448) sdst | [104448,104960) b1s
  __shared__ __align__(16) char lds[104960];
  f16* eh_s = (f16*)lds;
  char* bbuf = lds;
  int* ssrc = (int*)(lds + 102400);
  int* sdst = (int*)(lds + 103424);
  float* b1s = (float*)(lds + 104448);

  int t = threadIdx.x;
  int e_base = blockIdx.x * 256;

  // ---- phase 0: indices, b1, v gather -> vT (one edge per thread)
  {
    int eg = e_base + t;
    bool valid = eg < NEDGE;
    int si = valid ? src[eg] : 0;
    ssrc[t] = si;
    sdst[t] = valid ? dst[eg] : 0;
    if (t < 128) b1s[t] = b1[t];
    const f4* nr = (const f4*)(node + (long)si * 64);
    f16* vrow = (f16*)(lds + 65536 + t * 144);
#pragma unroll
    for (int b = 0; b < 8; ++b) {
      f4 v0 = nr[b * 2], v1 = nr[b * 2 + 1];
      h8 pk;
#pragma unroll
      for (int m = 0; m < 4; ++m) { pk[m] = (f16)v0[m]; pk[4 + m] = (f16)v1[m]; }
      *(h8*)(vrow + b * 8) = pk;
    }
  }
  __syncthreads();

  int wave = t >> 6, lane = t & 63;
  int l15 = lane & 15, lq = lane >> 4;
  int ew0 = wave * 64;  // this wave's edge slice (local)

  // ---- phase 1: eh = relu(edge @ W1^T + b1); A from global edgeh, two n-halves
  {
    h8 afr[4][2];
#pragma unroll
    for (int g = 0; g < 4; ++g)
#pragma unroll
      for (int s = 0; s < 2; ++s)
        afr[g][s] = *(const h8*)(edgeh + (long)(e_base + ew0 + g * 16 + l15) * 64 + s * 32 + lq * 8);
#pragma unroll
    for (int nh = 0; nh < 2; ++nh) {
      h8 bfr[2][4];
#pragma unroll
      for (int s = 0; s < 2; ++s)
#pragma unroll
        for (int tt = 0; tt < 4; ++tt)
          bfr[s][tt] = *(const h8*)(w1g + ((s * 8 + nh * 4 + tt) * 64 + lane) * 8);
      f4 acc_eh[4][4];
#pragma unroll
      for (int g = 0; g < 4; ++g)
#pragma unroll
        for (int tt = 0; tt < 4; ++tt) acc_eh[g][tt] = (f4){0.f, 0.f, 0.f, 0.f};
#pragma unroll
      for (int s = 0; s < 2; ++s)
#pragma unroll
        for (int g = 0; g < 4; ++g)
#pragma unroll
          for (int tt = 0; tt < 4; ++tt)
            acc_eh[g][tt] = __builtin_amdgcn_mfma_f32_16x16x32_f16(afr[g][s], bfr[s][tt], acc_eh[g][tt], 0, 0, 0);
      // write eh tile to LDS (swizzled granules), + b1 + relu
#pragma unroll
      for (int g = 0; g < 4; ++g)
#pragma unroll
        for (int tt = 0; tt < 4; ++tt) {
          int n = (nh * 4 + tt) * 16 + l15;
          int jg = n >> 3;
#pragma unroll
          for (int r = 0; r < 4; ++r) {
            int e = ew0 + g * 16 + lq * 4 + r;
            float val = fmaxf(acc_eh[g][tt][r] + b1s[n], 0.f);
            eh_s[(e * 16 + (jg ^ (e & 15))) * 8 + (n & 7)] = (f16)val;
          }
        }
    }
  }
  __syncthreads();

  // ---- phase 2: eh fragments -> registers (period-128 in K)
  h8 ehreg[4][4];
#pragma unroll
  for (int g = 0; g < 4; ++g) {
    int e = ew0 + g * 16 + l15;
#pragma unroll
    for (int s = 0; s < 4; ++s)
      ehreg[g][s] = *(const h8*)(eh_s + (e * 16 + ((s * 4 + lq) ^ (e & 15))) * 8);
  }
  __syncthreads();  // eh_s dead -> Bdbuf region free

  // prologue: DMA chunk 0 (32KB) into bbuf[0]
  const char* w2b = (const char*)w2g;
#pragma unroll
  for (int r = 0; r < 8; ++r) async16(w2b + r * 4096 + t * 16, bbuf + r * 4096 + t * 16);

  // ---- phase 3: 32 hp iterations (K=256 each = 2 h-chunks), B double-buffered
  f4 acc[4][4];
#pragma unroll
  for (int g = 0; g < 4; ++g)
#pragma unroll
    for (int tt = 0; tt < 4; ++tt) acc[g][tt] = (f4){0.f, 0.f, 0.f, 0.f};

#pragma unroll 1
  for (int hpb = 0; hpb < 8; ++hpb) {
    h8 vh8[4];
#pragma unroll
    for (int g = 0; g < 4; ++g)
      vh8[g] = *(const h8*)(lds + 65536 + (ew0 + g * 16 + l15) * 144 + hpb * 16);
#pragma unroll
    for (int hpi = 0; hpi < 4; ++hpi) {
      int hp = hpb * 4 + hpi;
      __syncthreads();  // chunk hp landed; previous buffer's reads retired
      {
        const char* gsrc = w2b + (long)(hp + 1) * 32768;  // hp=31 overreads w1g+wg: harmless
        char* ldst = bbuf + ((hp + 1) & 1) * 32768;
#pragma unroll
        for (int r = 0; r < 8; ++r) async16(gsrc + r * 4096 + t * 16, ldst + r * 4096 + t * 16);
      }
      const char* bp = bbuf + (hp & 1) * 32768;
#pragma unroll
      for (int sub = 0; sub < 2; ++sub) {
        const f16* bc = (const f16*)(bp + sub * 16384);
        const int hh = hpi * 2 + sub;  // static 0..7
#pragma unroll
        for (int s = 0; s < 4; ++s) {
          h8 bf[4];
#pragma unroll
          for (int tt = 0; tt < 4; ++tt)
            bf[tt] = *(const h8*)(bc + ((s * 4 + tt) * 64 + lane) * 8);
#pragma unroll
          for (int g = 0; g < 4; ++g) {
            h8 a = ehreg[g][s] * vh8[g][hh];
#pragma unroll
            for (int tt = 0; tt < 4; ++tt)
              acc[g][tt] = __builtin_amdgcn_mfma_f32_16x16x32_f16(a, bf[tt], acc[g][tt], 0, 0, 0);
          }
        }
      }
    }
  }

  // ---- epilogue: + nb[src], atomic scatter to agg[dst]
#pragma unroll
  for (int g = 0; g < 4; ++g)
#pragma unroll
    for (int tt = 0; tt < 4; ++tt)
#pragma unroll
      for (int r = 0; r < 4; ++r) {
        int el = ew0 + g * 16 + lq * 4 + r;
        if (e_base + el < NEDGE) {
          int n = tt * 16 + l15;
          float v = acc[g][tt][r] + nbt[(long)ssrc[el] * 64 + n];
          atomicAdd(&agg[(long)sdst[el] * 64 + n], v);
        }
      }
}

// ---------------- GRU + LayerNorm via MFMA: 128 nodes/block, 4 waves M-split.
__global__ __launch_bounds__(256) void k_node(const float* __restrict__ agg, const float* __restrict__ hid,
                                              const f16* __restrict__ wg,
                                              const float* __restrict__ bih, const float* __restrict__ bhh,
                                              const float* __restrict__ gamma, const float* __restrict__ beta,
                                              float* __restrict__ out) {
  __shared__ __align__(16) f16 xh_s[128 * 136];
  __shared__ float bsum[128], bin_s[64], bhn_s[64], gam_s[64], bet_s[64];
  int t = threadIdx.x;
  int n0 = blockIdx.x * 128;

  if (t < 128) bsum[t] = bih[t] + bhh[t];
  else if (t < 192) bin_s[t - 128] = bih[t];
  else bhn_s[t - 192] = bhh[t - 64];
  if (t < 64) gam_s[t] = gamma[t];
  else if (t < 128) bet_s[t - 64] = beta[t - 64];

  {  // stage A = [relu(agg) | hid] as f16
    int m = t >> 1, half = t & 1;
    int mg = n0 + m;
    bool vld = mg < NNODE;
    const float* sp = half ? (hid + (long)mg * 64) : (agg + (long)mg * 64);
#pragma unroll
    for (int jj = 0; jj < 8; ++jj) {
      f4 v0 = {0, 0, 0, 0}, v1 = {0, 0, 0, 0};
      if (vld) { v0 = *(const f4*)(sp + jj * 8); v1 = *(const f4*)(sp + jj * 8 + 4); }
      h8 pk;
#pragma unroll
      for (int m2 = 0; m2 < 4; ++m2) {
        pk[m2] = (f16)(half ? v0[m2] : fmaxf(v0[m2], 0.f));
        pk[4 + m2] = (f16)(half ? v1[m2] : fmaxf(v1[m2], 0.f));
      }
      *(h8*)(xh_s + m * 136 + half * 64 + jj * 8) = pk;
    }
  }
  __syncthreads();

  int wave = t >> 6, lane = t & 63;
  int l15 = lane & 15, lq = lane >> 4;

  f4 acc[2][16];
#pragma unroll
  for (int g = 0; g < 2; ++g)
#pragma unroll
    for (int tt = 0; tt < 16; ++tt) acc[g][tt] = (f4){0.f, 0.f, 0.f, 0.f};

#pragma unroll
  for (int s = 0; s < 4; ++s) {
    h8 a0 = *(const h8*)(xh_s + (wave * 32 + l15) * 136 + s * 32 + lq * 8);
    h8 a1 = *(const h8*)(xh_s + (wave * 32 + 16 + l15) * 136 + s * 32 + lq * 8);
#pragma unroll
    for (int tt = 0; tt < 16; ++tt) {
      h8 b = *(const h8*)(wg + ((s * 16 + tt) * 64 + lane) * 8);
      acc[0][tt] = __builtin_amdgcn_mfma_f32_16x16x32_f16(a0, b, acc[0][tt], 0, 0, 0);
      acc[1][tt] = __builtin_amdgcn_mfma_f32_16x16x32_f16(a1, b, acc[1][tt], 0, 0, 0);
    }
  }

#pragma unroll
  for (int g = 0; g < 2; ++g)
#pragma unroll
    for (int r = 0; r < 4; ++r) {
      int mg = n0 + wave * 32 + g * 16 + lq * 4 + r;
      bool vld = mg < NNODE;
      float o[4], ssum = 0.f, s2 = 0.f;
#pragma unroll
      for (int t0 = 0; t0 < 4; ++t0) {
        int f = t0 * 16 + l15;
        float rpre = acc[g][t0][r] + bsum[f];
        float zpre = acc[g][4 + t0][r] + bsum[64 + f];
        float ginv = acc[g][8 + t0][r] + bin_s[f];
        float ghnv = acc[g][12 + t0][r] + bhn_s[f];
        float rr = 1.f / (1.f + __expf(-rpre));
        float zz = 1.f / (1.f + __expf(-zpre));
        float hv = vld ? hid[(long)mg * 64 + f] : 0.f;
        float nn = tanhf(ginv + rr * ghnv);
        float oo = (1.f - zz) * nn + zz * hv;
        o[t0] = oo; ssum += oo; s2 += oo * oo;
      }
#pragma unroll
      for (int d = 1; d < 16; d <<= 1) {
        ssum += __shfl_xor(ssum, d);
        s2 += __shfl_xor(s2, d);
      }
      float mu = ssum * (1.f / 64.f);
      float var = s2 * (1.f / 64.f) - mu * mu;
      float rstd = rsqrtf(var + 1e-5f);
      if (vld)
#pragma unroll
        for (int t0 = 0; t0 < 4; ++t0) {
          int f = t0 * 16 + l15;
          out[(long)mg * 64 + f] = (o[t0] - mu) * rstd * gam_s[f] + bet_s[f];
        }
    }
}

extern "C" void kernel_launch(void* const* d_in, const int* in_sizes, int n_in,
                              void* d_out, int out_size, void* d_ws, size_t ws_size,
                              hipStream_t stream) {
  const float* node = (const float*)d_in[0];
  const float* edge = (const float*)d_in[1];
  const float* hid = (const float*)d_in[2];
  const int* src = (const int*)d_in[3];
  const int* dst = (const int*)d_in[4];
  const float* W1 = (const float*)d_in[5];
  const float* b1 = (const float*)d_in[6];
  const float* W2 = (const float*)d_in[7];
  const float* b2 = (const float*)d_in[8];
  const float* Wih = (const float*)d_in[9];
  const float* Whh = (const float*)d_in[10];
  const float* bih = (const float*)d_in[11];
  const float* bhh = (const float*)d_in[12];
  const float* gamma = (const float*)d_in[13];
  const float* beta = (const float*)d_in[14];

  char* ws = (char*)d_ws;
  f16* edgeh = (f16*)(ws + O_EDGEH);
  f16* w2g = (f16*)(ws + O_W2G);
  f16* w1g = (f16*)(ws + O_W1G);
  f16* wg = (f16*)(ws + O_WG);
  float* nb = (float*)(ws + O_NB);
  float* agg = (float*)(ws + O_AGG);

  k_prep<<<4714, 256, 0, stream>>>(edge, W1, W2, b2, node, Wih, Whh, edgeh, w1g, w2g, wg, nb, agg);
  k_msg<<<196, 256, 0, stream>>>(node, src, dst, edgeh, w1g, w2g, b1, nb, agg);
  k_node<<<94, 256, 0, stream>>>(agg, hid, wg, bih, bhh, gamma, beta, (float*)d_out);
}

// Round 5
// 186.514 us; speedup vs baseline: 1.1771x; 1.1487x over previous
//
#include <hip/hip_runtime.h>

#define H 64
#define NEDGE 50000
#define NNODE 12000
#define EPAD 50176

typedef _Float16 f16;
typedef _Float16 h8 __attribute__((ext_vector_type(8)));
typedef float f4 __attribute__((ext_vector_type(4)));
typedef float fv16 __attribute__((ext_vector_type(16)));

// workspace layout (bytes)
#define O_EDGEH 0ull            // edge f16 padded [50176][64]        = 6,422,528
#define O_W2G   6422528ull      // swizzled W2 f16 (64 chunks x 16KB) = 1,048,576
#define O_B2G   7471104ull      // swizzled b2 f16 (K=64 chunk, 8KB)  — MUST follow w2g (tail DMA)
#define O_W1G   7479296ull      // swizzled W1 f16 (16KB) — absorbs b2g-chunk 8KB overread
#define O_WG    7495680ull      // GRU combined weights f16 (64KB)
#define O_AGG   7561216ull      // agg f32 [12000][64]                = 3,072,000

__device__ __forceinline__ void async16(const void* g, void* l) {
  __builtin_amdgcn_global_load_lds((const __attribute__((address_space(1))) void*)g,
                                   (__attribute__((address_space(3))) void*)l, 16, 0, 0);
}

__device__ __forceinline__ fv16 zero16() {
  fv16 z;
#pragma unroll
  for (int i = 0; i < 16; ++i) z[i] = 0.f;
  return z;
}

// ---------------- prep: agg zero, edge->f16, W2/b2/W1/Wgru -> 32x32x16 MFMA-B granule order
// w2g: chunk h in [0,64); granule g=(s*2+nh)*64+l, elem i: W2[(h*64 + nh*32+(l&31))*128 + s*16+((l>>5)<<3)+i]
// b2g: granule g=(s*2+nh)*64+l (s<4), elem i: b2[(s*16+((l>>5)<<3)+i)*64 + nh*32+(l&31)]
// w1g: granule g=(s*4+nt)*64+l (s<4,nt<4), elem i: W1[(nt*32+(l&31))*64 + s*16+((l>>5)<<3)+i]
__global__ __launch_bounds__(256) void k_prep(const float* __restrict__ edge, const float* __restrict__ W1,
                                              const float* __restrict__ W2, const float* __restrict__ b2,
                                              const float* __restrict__ Wih, const float* __restrict__ Whh,
                                              f16* __restrict__ edgeh, f16* __restrict__ w1g, f16* __restrict__ w2g,
                                              f16* __restrict__ b2g, f16* __restrict__ wg, float* __restrict__ agg) {
  int bid = blockIdx.x;
  int t = threadIdx.x;
  if (bid < 750) {  // agg zero
    int id = bid * 256 + t;
    *(f4*)(agg + (long)id * 4) = (f4){0.f, 0.f, 0.f, 0.f};
    return;
  }
  if (bid < 2318) {  // edgeh cast, 8 elems/thread (EPAD rows, pad zeroed)
    long id8 = (long)(bid - 750) * 256 + t;
    long e = id8 >> 3;
    int c = (int)(id8 & 7) * 8;
    h8 o = {};
    if (e < NEDGE) {
      const float* p = edge + e * 64 + c;
      f4 v0 = *(const f4*)p, v1 = *(const f4*)(p + 4);
#pragma unroll
      for (int j = 0; j < 4; ++j) { o[j] = (f16)v0[j]; o[4 + j] = (f16)v1[j]; }
    }
    *(h8*)(edgeh + e * 64 + c) = o;
    return;
  }
  if (bid < 4366) {  // w2g: 524288 f16
    int id = (bid - 2318) * 256 + t;
    int i = id & 7, l = (id >> 3) & 63, nh = (id >> 9) & 1, s = (id >> 10) & 7, h = id >> 13;
    int n = nh * 32 + (l & 31), j = s * 16 + ((l >> 5) << 3) + i;
    w2g[id] = (f16)W2[(h * 64 + n) * 128 + j];
    return;
  }
  if (bid < 4382) {  // b2g: 4096 f16
    int id = (bid - 4366) * 256 + t;
    int i = id & 7, l = (id >> 3) & 63, nh = (id >> 9) & 1, s = id >> 10;
    int n = nh * 32 + (l & 31), k = s * 16 + ((l >> 5) << 3) + i;
    b2g[id] = (f16)b2[k * 64 + n];
    return;
  }
  if (bid < 4414) {  // w1g: 8192 f16
    int id = (bid - 4382) * 256 + t;
    int i = id & 7, l = (id >> 3) & 63, nt = (id >> 9) & 3, s = id >> 11;
    int n = nt * 32 + (l & 31), k = s * 16 + ((l >> 5) << 3) + i;
    w1g[id] = (f16)W1[n * 64 + k];
    return;
  }
  // wg: GRU combined B matrix [128k][256n] in 16x16x32 granule order, 32768 f16
  {
    int id = (bid - 4414) * 256 + t;
    int ii = id & 7, l = (id >> 3) & 63, tt = (id >> 9) & 15, s = id >> 13;
    int k = s * 32 + ((l >> 4) << 3) + ii, n = tt * 16 + (l & 15);
    float v;
    if (n < 128) v = (k < 64) ? Wih[n * 64 + k] : Whh[n * 64 + (k - 64)];
    else if (n < 192) v = (k < 64) ? Wih[n * 64 + k] : 0.f;
    else v = (k < 64) ? 0.f : Whh[(n - 64) * 64 + (k - 64)];
    wg[id] = (f16)v;
  }
}

// ---------------- fused msg kernel: 128 edges/block, 4 waves 2Mx2N (wave M=64, N=32), 32x32x16 MFMA.
// eh computed in-kernel via MFMA; eh fragments register-resident for the K=8192 loop;
// B double-buffered in LDS (16KB chunks) via global_load_lds; b2 folded as K=64 tail chunk.
// LDS 52736 B -> 3 blocks/CU.
__global__ __launch_bounds__(256, 3) void k_msg(const float* __restrict__ node,
                                                const int* __restrict__ src, const int* __restrict__ dst,
                                                const f16* __restrict__ edgeh, const f16* __restrict__ w1g,
                                                const f16* __restrict__ w2g, const float* __restrict__ b1,
                                                float* __restrict__ agg) {
  // [0,32768) bbuf dbuf (K-loop) / eh_s (phases 1-2, 128 rows x 256B)
  // [32768,51200) vT f16 [128 e][72] (pitch 144B, granule (e,hb) = v[e][8hb..8hb+7])
  // [51200,51712) ssrc | [51712,52224) sdst | [52224,52736) b1s
  __shared__ __align__(16) char lds[52736];
  f16* eh_s = (f16*)lds;
  char* bbuf = lds;
  f16* vT = (f16*)(lds + 32768);
  int* ssrc = (int*)(lds + 51200);
  int* sdst = (int*)(lds + 51712);
  float* b1s = (float*)(lds + 52224);

  int t = threadIdx.x;
  int e_base = blockIdx.x * 128;

  // ---- phase 0: indices, b1, v gather -> vT
  if (t < 128) {
    int eg = e_base + t;
    bool valid = eg < NEDGE;
    ssrc[t] = valid ? src[eg] : 0;
    sdst[t] = valid ? dst[eg] : 0;
  } else {
    b1s[t - 128] = b1[t - 128];
  }
  {
    int e = t >> 1, half = t & 1;
    int eg = e_base + e;
    int si = (eg < NEDGE) ? src[eg] : 0;
    const f4* nr = (const f4*)(node + (long)si * 64 + half * 32);
#pragma unroll
    for (int b = 0; b < 4; ++b) {
      f4 v0 = nr[b * 2], v1 = nr[b * 2 + 1];
      h8 pk;
#pragma unroll
      for (int m = 0; m < 4; ++m) { pk[m] = (f16)v0[m]; pk[4 + m] = (f16)v1[m]; }
      *(h8*)(vT + e * 72 + (half * 4 + b) * 8) = pk;
    }
  }
  __syncthreads();

  int wave = t >> 6, lane = t & 63;
  int wm = wave & 1, wn = wave >> 1;
  int l31 = lane & 31, lh = lane >> 5;

  // ---- phase 1: eh = relu(edge @ W1^T + b1), M=128/N=128/K=64, wave tile 64x64
  {
    h8 afr[2][4];
#pragma unroll
    for (int mt = 0; mt < 2; ++mt)
#pragma unroll
      for (int s = 0; s < 4; ++s)
        afr[mt][s] = *(const h8*)(edgeh + (long)(e_base + wm * 64 + mt * 32 + l31) * 64 + s * 16 + lh * 8);
    h8 bfr[2][4];
#pragma unroll
    for (int nt = 0; nt < 2; ++nt)
#pragma unroll
      for (int s = 0; s < 4; ++s)
        bfr[nt][s] = *(const h8*)(w1g + ((s * 4 + wn * 2 + nt) * 64 + lane) * 8);
    fv16 acc_eh[2][2];
#pragma unroll
    for (int mt = 0; mt < 2; ++mt)
#pragma unroll
      for (int nt = 0; nt < 2; ++nt) acc_eh[mt][nt] = zero16();
#pragma unroll
    for (int s = 0; s < 4; ++s)
#pragma unroll
      for (int mt = 0; mt < 2; ++mt)
#pragma unroll
        for (int nt = 0; nt < 2; ++nt)
          acc_eh[mt][nt] = __builtin_amdgcn_mfma_f32_32x32x16_f16(afr[mt][s], bfr[nt][s], acc_eh[mt][nt], 0, 0, 0);
    // write eh tile to LDS, swizzled granules, + b1 + relu
#pragma unroll
    for (int mt = 0; mt < 2; ++mt)
#pragma unroll
      for (int nt = 0; nt < 2; ++nt)
#pragma unroll
        for (int r = 0; r < 16; ++r) {
          int row = (r & 3) + 8 * (r >> 2) + 4 * lh;
          int e = wm * 64 + mt * 32 + row;
          int n = wn * 64 + nt * 32 + l31;
          float val = fmaxf(acc_eh[mt][nt][r] + b1s[n], 0.f);
          int o = n >> 3;
          eh_s[e * 128 + ((o ^ (e & 15)) << 3) + (n & 7)] = (f16)val;
        }
  }
  __syncthreads();

  // ---- phase 2: eh fragments -> registers (j period 128 in K)
  h8 ehreg[2][8];
#pragma unroll
  for (int mt = 0; mt < 2; ++mt) {
    int e = wm * 64 + mt * 32 + l31;
#pragma unroll
    for (int s = 0; s < 8; ++s) {
      int o = (s * 2 + lh) ^ (e & 15);
      ehreg[mt][s] = *(const h8*)(eh_s + e * 128 + o * 8);
    }
  }
  __syncthreads();  // eh_s dead -> bbuf region free

  // prologue: DMA chunk 0 (16KB)
  const char* w2b = (const char*)w2g;
#pragma unroll
  for (int r = 0; r < 4; ++r) async16(w2b + r * 4096 + t * 16, bbuf + r * 4096 + t * 16);

  // ---- phase 3: 64 h iterations (K=128 each), B LDS double-buffered
  fv16 acc[2];
  acc[0] = zero16(); acc[1] = zero16();
  const f16* vrow0 = vT + (wm * 64 + l31) * 72;
  const f16* vrow1 = vT + (wm * 64 + 32 + l31) * 72;

#pragma unroll 1
  for (int hb = 0; hb < 8; ++hb) {
    h8 vh0 = *(const h8*)(vrow0 + hb * 8);
    h8 vh1 = *(const h8*)(vrow1 + hb * 8);
#pragma unroll
    for (int hh = 0; hh < 8; ++hh) {
      int h = hb * 8 + hh;
      __syncthreads();  // chunk h landed; buffer (h+1)&1's readers retired
      {
        const char* gsrc = w2b + (long)(h + 1) * 16384;  // h=63 loads b2g chunk (+8KB overread into w1g: unused)
        char* ldst = bbuf + ((h + 1) & 1) * 16384;
#pragma unroll
        for (int r = 0; r < 4; ++r) async16(gsrc + r * 4096 + t * 16, ldst + r * 4096 + t * 16);
      }
      const f16* bp = (const f16*)(bbuf + (h & 1) * 16384) + (wn * 64 + lane) * 8;
      f16 v0 = vh0[hh], v1 = vh1[hh];
#pragma unroll
      for (int s = 0; s < 8; ++s) {
        h8 bf = *(const h8*)(bp + s * 1024);
        h8 a0 = ehreg[0][s] * v0;
        acc[0] = __builtin_amdgcn_mfma_f32_32x32x16_f16(a0, bf, acc[0], 0, 0, 0);
        h8 a1 = ehreg[1][s] * v1;
        acc[1] = __builtin_amdgcn_mfma_f32_32x32x16_f16(a1, bf, acc[1], 0, 0, 0);
      }
    }
  }
  // ---- bias tail chunk (b2, K=64; already in bbuf[0] from h=63 prefetch): A = v directly
  __syncthreads();
  {
    const f16* bp = (const f16*)bbuf + (wn * 64 + lane) * 8;
#pragma unroll
    for (int s = 0; s < 4; ++s) {
      h8 bf = *(const h8*)(bp + s * 1024);
      h8 a0 = *(const h8*)(vrow0 + (s * 2 + lh) * 8);
      h8 a1 = *(const h8*)(vrow1 + (s * 2 + lh) * 8);
      acc[0] = __builtin_amdgcn_mfma_f32_32x32x16_f16(a0, bf, acc[0], 0, 0, 0);
      acc[1] = __builtin_amdgcn_mfma_f32_32x32x16_f16(a1, bf, acc[1], 0, 0, 0);
    }
  }

  // ---- epilogue: atomic scatter to agg[dst]. col n = wn*32 + l31
  int n = wn * 32 + l31;
#pragma unroll
  for (int mt = 0; mt < 2; ++mt)
#pragma unroll
    for (int r = 0; r < 16; ++r) {
      int el = wm * 64 + mt * 32 + (r & 3) + 8 * (r >> 2) + 4 * lh;
      if (e_base + el < NEDGE)
        atomicAdd(&agg[(long)sdst[el] * 64 + n], acc[mt][r]);
    }
}

// ---------------- GRU + LayerNorm via MFMA: 128 nodes/block, 4 waves M-split.
__global__ __launch_bounds__(256) void k_node(const float* __restrict__ agg, const float* __restrict__ hid,
                                              const f16* __restrict__ wg,
                                              const float* __restrict__ bih, const float* __restrict__ bhh,
                                              const float* __restrict__ gamma, const float* __restrict__ beta,
                                              float* __restrict__ out) {
  __shared__ __align__(16) f16 xh_s[128 * 136];
  __shared__ float bsum[128], bin_s[64], bhn_s[64], gam_s[64], bet_s[64];
  int t = threadIdx.x;
  int n0 = blockIdx.x * 128;

  if (t < 128) bsum[t] = bih[t] + bhh[t];
  else if (t < 192) bin_s[t - 128] = bih[t];
  else bhn_s[t - 192] = bhh[t - 64];
  if (t < 64) gam_s[t] = gamma[t];
  else if (t < 128) bet_s[t - 64] = beta[t - 64];

  {  // stage A = [relu(agg) | hid] as f16
    int m = t >> 1, half = t & 1;
    int mg = n0 + m;
    bool vld = mg < NNODE;
    const float* sp = half ? (hid + (long)mg * 64) : (agg + (long)mg * 64);
#pragma unroll
    for (int jj = 0; jj < 8; ++jj) {
      f4 v0 = {0, 0, 0, 0}, v1 = {0, 0, 0, 0};
      if (vld) { v0 = *(const f4*)(sp + jj * 8); v1 = *(const f4*)(sp + jj * 8 + 4); }
      h8 pk;
#pragma unroll
      for (int m2 = 0; m2 < 4; ++m2) {
        pk[m2] = (f16)(half ? v0[m2] : fmaxf(v0[m2], 0.f));
        pk[4 + m2] = (f16)(half ? v1[m2] : fmaxf(v1[m2], 0.f));
      }
      *(h8*)(xh_s + m * 136 + half * 64 + jj * 8) = pk;
    }
  }
  __syncthreads();

  int wave = t >> 6, lane = t & 63;
  int l15 = lane & 15, lq = lane >> 4;

  f4 acc[2][16];
#pragma unroll
  for (int g = 0; g < 2; ++g)
#pragma unroll
    for (int tt = 0; tt < 16; ++tt) acc[g][tt] = (f4){0.f, 0.f, 0.f, 0.f};

#pragma unroll
  for (int s = 0; s < 4; ++s) {
    h8 a0 = *(const h8*)(xh_s + (wave * 32 + l15) * 136 + s * 32 + lq * 8);
    h8 a1 = *(const h8*)(xh_s + (wave * 32 + 16 + l15) * 136 + s * 32 + lq * 8);
#pragma unroll
    for (int tt = 0; tt < 16; ++tt) {
      h8 b = *(const h8*)(wg + ((s * 16 + tt) * 64 + lane) * 8);
      acc[0][tt] = __builtin_amdgcn_mfma_f32_16x16x32_f16(a0, b, acc[0][tt], 0, 0, 0);
      acc[1][tt] = __builtin_amdgcn_mfma_f32_16x16x32_f16(a1, b, acc[1][tt], 0, 0, 0);
    }
  }

#pragma unroll
  for (int g = 0; g < 2; ++g)
#pragma unroll
    for (int r = 0; r < 4; ++r) {
      int mg = n0 + wave * 32 + g * 16 + lq * 4 + r;
      bool vld = mg < NNODE;
      float o[4], ssum = 0.f, s2 = 0.f;
#pragma unroll
      for (int t0 = 0; t0 < 4; ++t0) {
        int f = t0 * 16 + l15;
        float rpre = acc[g][t0][r] + bsum[f];
        float zpre = acc[g][4 + t0][r] + bsum[64 + f];
        float ginv = acc[g][8 + t0][r] + bin_s[f];
        float ghnv = acc[g][12 + t0][r] + bhn_s[f];
        float rr = 1.f / (1.f + __expf(-rpre));
        float zz = 1.f / (1.f + __expf(-zpre));
        float hv = vld ? hid[(long)mg * 64 + f] : 0.f;
        float nn = tanhf(ginv + rr * ghnv);
        float oo = (1.f - zz) * nn + zz * hv;
        o[t0] = oo; ssum += oo; s2 += oo * oo;
      }
#pragma unroll
      for (int d = 1; d < 16; d <<= 1) {
        ssum += __shfl_xor(ssum, d);
        s2 += __shfl_xor(s2, d);
      }
      float mu = ssum * (1.f / 64.f);
      float var = s2 * (1.f / 64.f) - mu * mu;
      float rstd = rsqrtf(var + 1e-5f);
      if (vld)
#pragma unroll
        for (int t0 = 0; t0 < 4; ++t0) {
          int f = t0 * 16 + l15;
          out[(long)mg * 64 + f] = (o[t0] - mu) * rstd * gam_s[f] + bet_s[f];
        }
    }
}

extern "C" void kernel_launch(void* const* d_in, const int* in_sizes, int n_in,
                              void* d_out, int out_size, void* d_ws, size_t ws_size,
                              hipStream_t stream) {
  const float* node = (const float*)d_in[0];
  const float* edge = (const float*)d_in[1];
  const float* hid = (const float*)d_in[2];
  const int* src = (const int*)d_in[3];
  const int* dst = (const int*)d_in[4];
  const float* W1 = (const float*)d_in[5];
  const float* b1 = (const float*)d_in[6];
  const float* W2 = (const float*)d_in[7];
  const float* b2 = (const float*)d_in[8];
  const float* Wih = (const float*)d_in[9];
  const float* Whh = (const float*)d_in[10];
  const float* bih = (const float*)d_in[11];
  const float* bhh = (const float*)d_in[12];
  const float* gamma = (const float*)d_in[13];
  const float* beta = (const float*)d_in[14];

  char* ws = (char*)d_ws;
  f16* edgeh = (f16*)(ws + O_EDGEH);
  f16* w2g = (f16*)(ws + O_W2G);
  f16* b2g = (f16*)(ws + O_B2G);
  f16* w1g = (f16*)(ws + O_W1G);
  f16* wg = (f16*)(ws + O_WG);
  float* agg = (float*)(ws + O_AGG);

  k_prep<<<4542, 256, 0, stream>>>(edge, W1, W2, b2, Wih, Whh, edgeh, w1g, w2g, b2g, wg, agg);
  k_msg<<<392, 256, 0, stream>>>(node, src, dst, edgeh, w1g, w2g, b1, agg);
  k_node<<<94, 256, 0, stream>>>(agg, hid, wg, bih, bhh, gamma, beta, (float*)d_out);
}